// Round 5
// baseline (220.145 us; speedup 1.0000x reference)
//
#include <hip/hip_runtime.h>

#define HD 256
#define LN_EPS 1e-5f
#define DEG_EPS 1e-6f
#define CAP 64

typedef __attribute__((ext_vector_type(8))) short short8;
typedef __attribute__((ext_vector_type(4))) short s16x4;
typedef __attribute__((ext_vector_type(4))) float f32x4;

__device__ inline unsigned short f2bf(float f) {
    union { float f; unsigned int u; } v; v.f = f;
    unsigned int r = v.u + 0x7FFFu + ((v.u >> 16) & 1u);
    return (unsigned short)(r >> 16);
}

// Convert weight matrices to bf16 once per launch (deterministic, tiny).
__global__ void prep_kernel(const float* __restrict__ msg_W,
                            const float* __restrict__ upd_W,
                            unsigned short* __restrict__ w1b,
                            unsigned short* __restrict__ w2b,
                            float* __restrict__ ucol) {
    int t = blockIdx.x * blockDim.x + threadIdx.x;
    if (t < 256 * 256) {
        w1b[t] = f2bf(msg_W[t]);
        int j = t >> 8, k = t & 255;
        w2b[t] = f2bf(upd_W[j * 257 + k]);
        if (k == 0) ucol[j] = upd_W[j * 257 + 256];
    }
}

// Bucket edges by dst: counts[] = degree, eidx[d*CAP + p] = src ids.
__global__ __launch_bounds__(256) void fill_kernel(
    const int* __restrict__ src, const int* __restrict__ dst,
    int* __restrict__ counts, int* __restrict__ eidx, int E) {
    int e = blockIdx.x * 256 + threadIdx.x;
    if (e >= E) return;
    int d = dst[e];
    int p = atomicAdd(&counts[d], 1);
    if (p < CAP) eidx[d * CAP + p] = src[e];
}

// One wave per constraint row; 4 rows per 256-thr block. 50K waves total
// (~195 queued waves/CU) so gather latency is hidden by TLP, not ILP.
// Emits pre-scaled bf16 agg row-major [num_con][256].
__global__ __launch_bounds__(256) void gather_kernel(
    const float* __restrict__ x_var, const int* __restrict__ counts,
    const int* __restrict__ eidx, unsigned short* __restrict__ agg,
    int num_con) {
    int row  = blockIdx.x * 4 + (threadIdx.x >> 6);
    int lane = threadIdx.x & 63;
    if (row >= num_con) return;
    int cnt = counts[row];
    int cgo = min(cnt, CAP);
    int sid = (lane < cgo) ? eidx[row * CAP + lane] : 0;
    float a0 = 0.f, a1 = 0.f, a2 = 0.f, a3 = 0.f;
#pragma unroll 1
    for (int i = 0; i < cgo; i += 4) {
        int s0 = __shfl(sid, i, 64);
        int s1 = __shfl(sid, i + 1, 64);
        int s2 = __shfl(sid, i + 2, 64);
        int s3 = __shfl(sid, i + 3, 64);
        float4 v0 = *(const float4*)(x_var + (long)s0 * HD + lane * 4);
        float4 v1 = *(const float4*)(x_var + (long)s1 * HD + lane * 4);
        float4 v2 = *(const float4*)(x_var + (long)s2 * HD + lane * 4);
        float4 v3 = *(const float4*)(x_var + (long)s3 * HD + lane * 4);
        float w1 = (i + 1 < cgo) ? 1.f : 0.f;
        float w2 = (i + 2 < cgo) ? 1.f : 0.f;
        float w3 = (i + 3 < cgo) ? 1.f : 0.f;
        a0 += v0.x + v1.x * w1 + v2.x * w2 + v3.x * w3;
        a1 += v0.y + v1.y * w1 + v2.y * w2 + v3.y * w3;
        a2 += v0.z + v1.z * w1 + v2.z * w2 + v3.z * w3;
        a3 += v0.w + v1.w * w1 + v2.w * w2 + v3.w * w3;
    }
    float sc = 1.0f / ((float)cnt + DEG_EPS);
    s16x4 o;
    o[0] = (short)f2bf(a0 * sc); o[1] = (short)f2bf(a1 * sc);
    o[2] = (short)f2bf(a2 * sc); o[3] = (short)f2bf(a3 * sc);
    *(s16x4*)(agg + (long)row * HD + lane * 4) = o;
}

// 256 thr (4 waves), 64 rows/block, wave owns 16 rows; gather-free.
// A-frags straight from global bf16 agg -> GEMM1 -> M in wave-private
// swizzled LDS -> GEMM2 (+clue,+bias) -> ReLU -> LayerNorm -> coalesced
// store via wave-private LDS fp32 restage. No barriers needed.
__global__ __launch_bounds__(256) void fused_kernel(
    const unsigned short* __restrict__ agg, const int* __restrict__ counts,
    const float* __restrict__ clue,
    const unsigned short* __restrict__ w1b, const float* __restrict__ msg_b,
    const unsigned short* __restrict__ w2b, const float* __restrict__ ucol,
    const float* __restrict__ upd_b,
    const float* __restrict__ ln_w, const float* __restrict__ ln_b,
    float* __restrict__ out, int num_con) {

    __shared__ unsigned short sM[64 * 256];   // 32 KB, wave-private 8KB slices

    const int tid  = threadIdx.x;
    const int w    = tid >> 6;
    const int lane = tid & 63;
    const int lr   = lane & 15;   // frag row (A) / col (B, D)
    const int lg   = lane >> 4;   // 0..3
    const int c0   = blockIdx.x * 64 + w * 16;   // wave's first row

    // ---- A fragments from global agg (bf16, pre-scaled) ----
    int arow = c0 + lr;
    bool av  = arow < num_con;
    int arc  = av ? arow : 0;
    const unsigned short* ap = agg + (long)arc * HD + lg * 8;
    short8 afrag[8];
#pragma unroll
    for (int ks = 0; ks < 8; ++ks)
        afrag[ks] = *(const short8*)(ap + ks * 32);
    float dv = av ? (float)counts[arow] : 0.0f;
    float tcoef = dv / (dv + DEG_EPS);            // deg/(deg+eps)

    // ---- GEMM1: 16 j-tiles, epilogue writes bf16 M into swizzled LDS ----
#pragma unroll 1
    for (int jt = 0; jt < 16; ++jt) {
        f32x4 acc = {0.f, 0.f, 0.f, 0.f};
        const unsigned short* bp = w1b + (jt * 16 + lr) * HD + lg * 8;
#pragma unroll
        for (int ks = 0; ks < 8; ++ks) {
            short8 b = *(const short8*)(bp + ks * 32);
            acc = __builtin_amdgcn_mfma_f32_16x16x32_bf16(afrag[ks], b, acc, 0, 0, 0);
        }
        float bj = msg_b[jt * 16 + lr];
#pragma unroll
        for (int q = 0; q < 4; ++q) {
            int rl = lg * 4 + q;                       // row in wave tile 0..15
            float trow = __shfl(tcoef, rl, 64);        // lane rl holds row rl's coef
            float m = acc[q] + trow * bj;
            int rf = w * 16 + rl;
            int byte = (rf * 512 + (jt * 16 + lr) * 2) ^ ((rf & 7) << 4);
            *(unsigned short*)((char*)sM + byte) = f2bf(m);
        }
    }

    // ---- A2 fragments from LDS ----
    short8 a2[8];
    {
        int rf = w * 16 + lr;
#pragma unroll
        for (int ks = 0; ks < 8; ++ks) {
            int byte = (rf * 512 + (ks * 32 + lg * 8) * 2) ^ ((rf & 7) << 4);
            a2[ks] = *(const short8*)((char*)sM + byte);
        }
    }

    // clue per epilogue row (row = c0 + lg*4 + q)
    float cl[4];
#pragma unroll
    for (int q = 0; q < 4; ++q) {
        int re = c0 + lg * 4 + q;
        cl[q] = (re < num_con) ? clue[re] : 0.0f;
    }

    // ---- GEMM2 + clue/bias + ReLU, results kept in registers ----
    float vv[16][4];
#pragma unroll 1
    for (int jt = 0; jt < 16; ++jt) {
        f32x4 acc = {0.f, 0.f, 0.f, 0.f};
        const unsigned short* bp = w2b + (jt * 16 + lr) * HD + lg * 8;
#pragma unroll
        for (int ks = 0; ks < 8; ++ks) {
            short8 b = *(const short8*)(bp + ks * 32);
            acc = __builtin_amdgcn_mfma_f32_16x16x32_bf16(a2[ks], b, acc, 0, 0, 0);
        }
        float uc = ucol[jt * 16 + lr];
        float bj = upd_b[jt * 16 + lr];
#pragma unroll
        for (int q = 0; q < 4; ++q) {
            float z = acc[q] + uc * cl[q] + bj;
            vv[jt][q] = fmaxf(z, 0.0f);
        }
    }

    // ---- LayerNorm over j (256) per row ----
    float sum[4] = {0.f, 0.f, 0.f, 0.f}, ssq[4] = {0.f, 0.f, 0.f, 0.f};
#pragma unroll
    for (int jt = 0; jt < 16; ++jt)
#pragma unroll
        for (int q = 0; q < 4; ++q) {
            float v = vv[jt][q];
            sum[q] += v; ssq[q] += v * v;
        }
#pragma unroll
    for (int m = 1; m < 16; m <<= 1) {
#pragma unroll
        for (int q = 0; q < 4; ++q) {
            sum[q] += __shfl_xor(sum[q], m, 64);
            ssq[q] += __shfl_xor(ssq[q], m, 64);
        }
    }
    float mu[4], rs[4];
#pragma unroll
    for (int q = 0; q < 4; ++q) {
        mu[q] = sum[q] * (1.0f / HD);
        float var = ssq[q] * (1.0f / HD) - mu[q] * mu[q];
        rs[q] = rsqrtf(var + LN_EPS);
    }

    // ---- coalesced store: wave-private fp32 restage, 2 passes of 8 rows ----
    float* sF = (float*)sM + w * 2048;             // 8 KB slice per wave
#pragma unroll 1
    for (int h = 0; h < 2; ++h) {
        if ((lg >> 1) == h) {                      // lanes owning rows 8h..8h+7
            int rl0 = (lg & 1) * 4;                // local row base 0 or 4
#pragma unroll
            for (int jt = 0; jt < 16; ++jt) {
                int j = jt * 16 + lr;
                float lwj = ln_w[j], lbj = ln_b[j];
#pragma unroll
                for (int q = 0; q < 4; ++q) {
                    float o = (vv[jt][q] - mu[q]) * rs[q] * lwj + lbj;
                    sF[(rl0 + q) * 256 + j] = o;
                }
            }
        }
#pragma unroll 1
        for (int r8 = 0; r8 < 8; ++r8) {
            int re = c0 + h * 8 + r8;
            if (re < num_con) {
                float4 v = *(const float4*)(sF + r8 * 256 + lane * 4);
                *(float4*)(out + (long)re * HD + lane * 4) = v;
            }
        }
    }
}

extern "C" void kernel_launch(void* const* d_in, const int* in_sizes, int n_in,
                              void* d_out, int out_size, void* d_ws, size_t ws_size,
                              hipStream_t stream) {
    const float* x_var = (const float*)d_in[0];
    const int*   src   = (const int*)d_in[1];
    const int*   dst   = (const int*)d_in[2];
    const float* clue  = (const float*)d_in[3];
    // d_in[4] = num_con scalar (derived from out_size instead)
    const float* msg_W = (const float*)d_in[5];
    const float* msg_b = (const float*)d_in[6];
    const float* upd_W = (const float*)d_in[7];
    const float* upd_b = (const float*)d_in[8];
    const float* ln_w  = (const float*)d_in[9];
    const float* ln_b  = (const float*)d_in[10];

    int E = in_sizes[1];
    int num_con = out_size / HD;

    char* ws = (char*)d_ws;
    int* counts = (int*)ws;                               // num_con ints
    int* eidx   = (int*)(ws + (((size_t)num_con * 4 + 255) & ~(size_t)255));
    char* after = (char*)(eidx + (size_t)num_con * CAP);  // num_con*CAP ints
    size_t aoff = ((size_t)(after - ws) + 255) & ~(size_t)255;
    unsigned short* agg = (unsigned short*)(ws + aoff);   // num_con*256 bf16
    size_t woff = (aoff + (size_t)num_con * HD * 2 + 255) & ~(size_t)255;
    unsigned short* w1b = (unsigned short*)(ws + woff);
    unsigned short* w2b = w1b + 256 * 256;
    float* ucol = (float*)(w2b + 256 * 256);

    (void)hipMemsetAsync(counts, 0, (size_t)num_con * 4, stream);

    prep_kernel<<<256, 256, 0, stream>>>(msg_W, upd_W, w1b, w2b, ucol);

    fill_kernel<<<(E + 255) / 256, 256, 0, stream>>>(src, dst, counts, eidx, E);

    gather_kernel<<<(num_con + 3) / 4, 256, 0, stream>>>(
        x_var, counts, eidx, agg, num_con);

    fused_kernel<<<(num_con + 63) / 64, 256, 0, stream>>>(
        agg, counts, clue, w1b, msg_b, w2b, ucol, upd_b, ln_w, ln_b,
        (float*)d_out, num_con);
}

// Round 6
// 201.092 us; speedup vs baseline: 1.0948x; 1.0948x over previous
//
#include <hip/hip_runtime.h>

#define HD 256
#define LN_EPS 1e-5f
#define DEG_EPS 1e-6f
#define CAP 64

typedef __attribute__((ext_vector_type(8))) short short8;
typedef __attribute__((ext_vector_type(4))) short s16x4;
typedef __attribute__((ext_vector_type(4))) float f32x4;

__device__ inline unsigned short f2bf(float f) {
    union { float f; unsigned int u; } v; v.f = f;
    unsigned int r = v.u + 0x7FFFu + ((v.u >> 16) & 1u);
    return (unsigned short)(r >> 16);
}
__device__ inline float bf2f(unsigned short h) {
    union { unsigned int u; float f; } v; v.u = ((unsigned int)h) << 16;
    return v.f;
}

// Convert weight matrices to bf16 once per launch (deterministic, tiny).
__global__ void prep_kernel(const float* __restrict__ msg_W,
                            const float* __restrict__ upd_W,
                            unsigned short* __restrict__ w1b,
                            unsigned short* __restrict__ w2b,
                            float* __restrict__ ucol) {
    int t = blockIdx.x * blockDim.x + threadIdx.x;
    if (t < 256 * 256) {
        w1b[t] = f2bf(msg_W[t]);
        int j = t >> 8, k = t & 255;
        w2b[t] = f2bf(upd_W[j * 257 + k]);
        if (k == 0) ucol[j] = upd_W[j * 257 + 256];
    }
}

// Bucket edges by dst: counts[] = degree, eidx[d*CAP + p] = src ids.
__global__ __launch_bounds__(256) void fill_kernel(
    const int* __restrict__ src, const int* __restrict__ dst,
    int* __restrict__ counts, int* __restrict__ eidx, int E) {
    int e = blockIdx.x * 256 + threadIdx.x;
    if (e >= E) return;
    int d = dst[e];
    int p = atomicAdd(&counts[d], 1);
    if (p < CAP) eidx[d * CAP + p] = src[e];
}

// One wave per constraint row; 4 rows per 256-thr block. 50K waves total,
// gather latency hidden by TLP. Emits pre-scaled bf16 agg [num_con][256].
__global__ __launch_bounds__(256) void gather_kernel(
    const float* __restrict__ x_var, const int* __restrict__ counts,
    const int* __restrict__ eidx, unsigned short* __restrict__ agg,
    int num_con) {
    int row  = blockIdx.x * 4 + (threadIdx.x >> 6);
    int lane = threadIdx.x & 63;
    if (row >= num_con) return;
    int cnt = counts[row];
    int cgo = min(cnt, CAP);
    int sid = (lane < cgo) ? eidx[row * CAP + lane] : 0;
    float a0 = 0.f, a1 = 0.f, a2 = 0.f, a3 = 0.f;
#pragma unroll 1
    for (int i = 0; i < cgo; i += 4) {
        int s0 = __shfl(sid, i, 64);
        int s1 = __shfl(sid, i + 1, 64);
        int s2 = __shfl(sid, i + 2, 64);
        int s3 = __shfl(sid, i + 3, 64);
        float4 v0 = *(const float4*)(x_var + (long)s0 * HD + lane * 4);
        float4 v1 = *(const float4*)(x_var + (long)s1 * HD + lane * 4);
        float4 v2 = *(const float4*)(x_var + (long)s2 * HD + lane * 4);
        float4 v3 = *(const float4*)(x_var + (long)s3 * HD + lane * 4);
        float w1 = (i + 1 < cgo) ? 1.f : 0.f;
        float w2 = (i + 2 < cgo) ? 1.f : 0.f;
        float w3 = (i + 3 < cgo) ? 1.f : 0.f;
        a0 += v0.x + v1.x * w1 + v2.x * w2 + v3.x * w3;
        a1 += v0.y + v1.y * w1 + v2.y * w2 + v3.y * w3;
        a2 += v0.z + v1.z * w1 + v2.z * w2 + v3.z * w3;
        a3 += v0.w + v1.w * w1 + v2.w * w2 + v3.w * w3;
    }
    float sc = 1.0f / ((float)cnt + DEG_EPS);
    s16x4 o;
    o[0] = (short)f2bf(a0 * sc); o[1] = (short)f2bf(a1 * sc);
    o[2] = (short)f2bf(a2 * sc); o[3] = (short)f2bf(a3 * sc);
    *(s16x4*)(agg + (long)row * HD + lane * 4) = o;
}

// 256 thr (4 waves), 64 rows/block, wave owns 16 rows; gather-free.
// GEMM1 (jt-unrolled x2, dual MFMA chains) -> M bf16 in wave-private
// swizzled LDS -> GEMM2 (dual chains, +clue,+bias,ReLU) with on-the-fly
// LN stats; z parked bf16 in same LDS -> LN-apply + coalesced store.
__global__ __launch_bounds__(256) void fused_kernel(
    const unsigned short* __restrict__ agg, const int* __restrict__ counts,
    const float* __restrict__ clue,
    const unsigned short* __restrict__ w1b, const float* __restrict__ msg_b,
    const unsigned short* __restrict__ w2b, const float* __restrict__ ucol,
    const float* __restrict__ upd_b,
    const float* __restrict__ ln_w, const float* __restrict__ ln_b,
    float* __restrict__ out, int num_con) {

    __shared__ unsigned short sM[64 * 256];   // 32 KB, wave-private 8KB slices
    __shared__ float muv[64], rsv[64];

    const int tid  = threadIdx.x;
    const int w    = tid >> 6;
    const int lane = tid & 63;
    const int lr   = lane & 15;   // frag row (A) / col (B, D)
    const int lg   = lane >> 4;   // 0..3
    const int c0   = blockIdx.x * 64 + w * 16;   // wave's first row

    // ---- A fragments from global agg (bf16, pre-scaled) ----
    int arow = c0 + lr;
    bool av  = arow < num_con;
    int arc  = av ? arow : 0;
    const unsigned short* ap = agg + (long)arc * HD + lg * 8;
    short8 afrag[8];
#pragma unroll
    for (int ks = 0; ks < 8; ++ks)
        afrag[ks] = *(const short8*)(ap + ks * 32);
    float dv = av ? (float)counts[arow] : 0.0f;
    float tcoef = dv / (dv + DEG_EPS);            // deg/(deg+eps)

    // hoisted: epilogue row coefs (jt-invariant); lane handles row lg*4+q
    float trow_[4];
#pragma unroll
    for (int q = 0; q < 4; ++q) trow_[q] = __shfl(tcoef, lg * 4 + q, 64);

    // ---- GEMM1: jt-unrolled x2, two independent MFMA chains ----
#pragma unroll 1
    for (int jt = 0; jt < 16; jt += 2) {
        f32x4 acc0 = {0.f, 0.f, 0.f, 0.f};
        f32x4 acc1 = {0.f, 0.f, 0.f, 0.f};
        const unsigned short* bp0 = w1b + (jt * 16 + lr) * HD + lg * 8;
        const unsigned short* bp1 = bp0 + 16 * HD;
#pragma unroll
        for (int ks = 0; ks < 8; ++ks) {
            short8 b0 = *(const short8*)(bp0 + ks * 32);
            short8 b1 = *(const short8*)(bp1 + ks * 32);
            acc0 = __builtin_amdgcn_mfma_f32_16x16x32_bf16(afrag[ks], b0, acc0, 0, 0, 0);
            acc1 = __builtin_amdgcn_mfma_f32_16x16x32_bf16(afrag[ks], b1, acc1, 0, 0, 0);
        }
        float bj0 = msg_b[jt * 16 + lr];
        float bj1 = msg_b[(jt + 1) * 16 + lr];
#pragma unroll
        for (int q = 0; q < 4; ++q) {
            int rl = lg * 4 + q;
            int rf = w * 16 + rl;
            float m0 = acc0[q] + trow_[q] * bj0;
            float m1 = acc1[q] + trow_[q] * bj1;
            int by0 = (rf * 512 + (jt * 16 + lr) * 2) ^ ((rf & 7) << 4);
            int by1 = (rf * 512 + ((jt + 1) * 16 + lr) * 2) ^ ((rf & 7) << 4);
            *(unsigned short*)((char*)sM + by0) = f2bf(m0);
            *(unsigned short*)((char*)sM + by1) = f2bf(m1);
        }
    }

    // ---- A2 fragments from LDS ----
    short8 a2[8];
    {
        int rf = w * 16 + lr;
#pragma unroll
        for (int ks = 0; ks < 8; ++ks) {
            int byte = (rf * 512 + (ks * 32 + lg * 8) * 2) ^ ((rf & 7) << 4);
            a2[ks] = *(const short8*)((char*)sM + byte);
        }
    }

    // clue per epilogue row (row = c0 + lg*4 + q)
    float cl[4];
#pragma unroll
    for (int q = 0; q < 4; ++q) {
        int re = c0 + lg * 4 + q;
        cl[q] = (re < num_con) ? clue[re] : 0.0f;
    }

    // ---- GEMM2 (dual chains) + clue/bias + ReLU; LN stats on the fly;
    //      z parked as bf16 back into sM (a2 already consumed) ----
    float sum[4] = {0.f, 0.f, 0.f, 0.f}, ssq[4] = {0.f, 0.f, 0.f, 0.f};
#pragma unroll 1
    for (int jt = 0; jt < 16; jt += 2) {
        f32x4 acc0 = {0.f, 0.f, 0.f, 0.f};
        f32x4 acc1 = {0.f, 0.f, 0.f, 0.f};
        const unsigned short* bp0 = w2b + (jt * 16 + lr) * HD + lg * 8;
        const unsigned short* bp1 = bp0 + 16 * HD;
#pragma unroll
        for (int ks = 0; ks < 8; ++ks) {
            short8 b0 = *(const short8*)(bp0 + ks * 32);
            short8 b1 = *(const short8*)(bp1 + ks * 32);
            acc0 = __builtin_amdgcn_mfma_f32_16x16x32_bf16(a2[ks], b0, acc0, 0, 0, 0);
            acc1 = __builtin_amdgcn_mfma_f32_16x16x32_bf16(a2[ks], b1, acc1, 0, 0, 0);
        }
        float uc0 = ucol[jt * 16 + lr],  bj0 = upd_b[jt * 16 + lr];
        float uc1 = ucol[(jt + 1) * 16 + lr], bj1 = upd_b[(jt + 1) * 16 + lr];
#pragma unroll
        for (int q = 0; q < 4; ++q) {
            int rl = lg * 4 + q;
            int rf = w * 16 + rl;
            float z0 = fmaxf(acc0[q] + uc0 * cl[q] + bj0, 0.0f);
            float z1 = fmaxf(acc1[q] + uc1 * cl[q] + bj1, 0.0f);
            sum[q] += z0 + z1;
            ssq[q] += z0 * z0 + z1 * z1;
            int by0 = (rf * 512 + (jt * 16 + lr) * 2) ^ ((rf & 7) << 4);
            int by1 = (rf * 512 + ((jt + 1) * 16 + lr) * 2) ^ ((rf & 7) << 4);
            *(unsigned short*)((char*)sM + by0) = f2bf(z0);
            *(unsigned short*)((char*)sM + by1) = f2bf(z1);
        }
    }

    // ---- LN stats reduce across the 16 lanes of each lg group ----
#pragma unroll
    for (int m = 1; m < 16; m <<= 1) {
#pragma unroll
        for (int q = 0; q < 4; ++q) {
            sum[q] += __shfl_xor(sum[q], m, 64);
            ssq[q] += __shfl_xor(ssq[q], m, 64);
        }
    }
    if (lr == 0) {
#pragma unroll
        for (int q = 0; q < 4; ++q) {
            float mu = sum[q] * (1.0f / HD);
            float var = ssq[q] * (1.0f / HD) - mu * mu;
            muv[w * 16 + lg * 4 + q] = mu;
            rsv[w * 16 + lg * 4 + q] = rsqrtf(var + LN_EPS);
        }
    }

    // ---- LN apply + coalesced store (wave-private LDS, no barrier) ----
    float4 lw4 = *(const float4*)(ln_w + lane * 4);
    float4 lb4 = *(const float4*)(ln_b + lane * 4);
#pragma unroll 1
    for (int r8 = 0; r8 < 16; ++r8) {
        int re = c0 + r8;
        if (re < num_con) {
            int rf = w * 16 + r8;
            int byte = (rf * 512 + lane * 8) ^ ((rf & 7) << 4);
            s16x4 z4 = *(const s16x4*)((char*)sM + byte);
            float mu_r = muv[rf], rs_r = rsv[rf];
            float4 o;
            o.x = (bf2f((unsigned short)z4[0]) - mu_r) * rs_r * lw4.x + lb4.x;
            o.y = (bf2f((unsigned short)z4[1]) - mu_r) * rs_r * lw4.y + lb4.y;
            o.z = (bf2f((unsigned short)z4[2]) - mu_r) * rs_r * lw4.z + lb4.z;
            o.w = (bf2f((unsigned short)z4[3]) - mu_r) * rs_r * lw4.w + lb4.w;
            *(float4*)(out + (long)re * HD + lane * 4) = o;
        }
    }
}

extern "C" void kernel_launch(void* const* d_in, const int* in_sizes, int n_in,
                              void* d_out, int out_size, void* d_ws, size_t ws_size,
                              hipStream_t stream) {
    const float* x_var = (const float*)d_in[0];
    const int*   src   = (const int*)d_in[1];
    const int*   dst   = (const int*)d_in[2];
    const float* clue  = (const float*)d_in[3];
    // d_in[4] = num_con scalar (derived from out_size instead)
    const float* msg_W = (const float*)d_in[5];
    const float* msg_b = (const float*)d_in[6];
    const float* upd_W = (const float*)d_in[7];
    const float* upd_b = (const float*)d_in[8];
    const float* ln_w  = (const float*)d_in[9];
    const float* ln_b  = (const float*)d_in[10];

    int E = in_sizes[1];
    int num_con = out_size / HD;

    char* ws = (char*)d_ws;
    int* counts = (int*)ws;                               // num_con ints
    int* eidx   = (int*)(ws + (((size_t)num_con * 4 + 255) & ~(size_t)255));
    char* after = (char*)(eidx + (size_t)num_con * CAP);  // num_con*CAP ints
    size_t aoff = ((size_t)(after - ws) + 255) & ~(size_t)255;
    unsigned short* agg = (unsigned short*)(ws + aoff);   // num_con*256 bf16
    size_t woff = (aoff + (size_t)num_con * HD * 2 + 255) & ~(size_t)255;
    unsigned short* w1b = (unsigned short*)(ws + woff);
    unsigned short* w2b = w1b + 256 * 256;
    float* ucol = (float*)(w2b + 256 * 256);

    (void)hipMemsetAsync(counts, 0, (size_t)num_con * 4, stream);

    prep_kernel<<<256, 256, 0, stream>>>(msg_W, upd_W, w1b, w2b, ucol);

    fill_kernel<<<(E + 255) / 256, 256, 0, stream>>>(src, dst, counts, eidx, E);

    gather_kernel<<<(num_con + 3) / 4, 256, 0, stream>>>(
        x_var, counts, eidx, agg, num_con);

    fused_kernel<<<(num_con + 63) / 64, 256, 0, stream>>>(
        agg, counts, clue, w1b, msg_b, w2b, ucol, upd_b, ln_w, ln_b,
        (float*)d_out, num_con);
}

// Round 7
// 147.364 us; speedup vs baseline: 1.4939x; 1.3646x over previous
//
#include <hip/hip_runtime.h>

#define HD 256
#define LN_EPS 1e-5f
#define DEG_EPS 1e-6f
#define CAP 64

typedef __attribute__((ext_vector_type(8))) short short8;
typedef __attribute__((ext_vector_type(4))) short s16x4;
typedef __attribute__((ext_vector_type(4))) float f32x4;

__device__ inline unsigned short f2bf(float f) {
    union { float f; unsigned int u; } v; v.f = f;
    unsigned int r = v.u + 0x7FFFu + ((v.u >> 16) & 1u);
    return (unsigned short)(r >> 16);
}

// Convert weight matrices to bf16 once per launch (deterministic, tiny).
__global__ void prep_kernel(const float* __restrict__ msg_W,
                            const float* __restrict__ upd_W,
                            unsigned short* __restrict__ w1b,
                            unsigned short* __restrict__ w2b,
                            float* __restrict__ ucol) {
    int t = blockIdx.x * blockDim.x + threadIdx.x;
    if (t < 256 * 256) {
        w1b[t] = f2bf(msg_W[t]);
        int j = t >> 8, k = t & 255;
        w2b[t] = f2bf(upd_W[j * 257 + k]);
        if (k == 0) ucol[j] = upd_W[j * 257 + 256];
    }
}

// Bucket edges by dst: counts[] = degree, eidx[d*CAP + p] = src ids.
__global__ __launch_bounds__(256) void fill_kernel(
    const int* __restrict__ src, const int* __restrict__ dst,
    int* __restrict__ counts, int* __restrict__ eidx, int E) {
    int e = blockIdx.x * 256 + threadIdx.x;
    if (e >= E) return;
    int d = dst[e];
    int p = atomicAdd(&counts[d], 1);
    if (p < CAP) eidx[d * CAP + p] = src[e];
}

// One wave per constraint row; 4 rows per 256-thr block. 50K waves total,
// gather latency hidden by TLP. Emits pre-scaled bf16 agg [num_con][256].
__global__ __launch_bounds__(256) void gather_kernel(
    const float* __restrict__ x_var, const int* __restrict__ counts,
    const int* __restrict__ eidx, unsigned short* __restrict__ agg,
    int num_con) {
    int row  = blockIdx.x * 4 + (threadIdx.x >> 6);
    int lane = threadIdx.x & 63;
    if (row >= num_con) return;
    int cnt = counts[row];
    int cgo = min(cnt, CAP);
    int sid = (lane < cgo) ? eidx[row * CAP + lane] : 0;
    float a0 = 0.f, a1 = 0.f, a2 = 0.f, a3 = 0.f;
#pragma unroll 1
    for (int i = 0; i < cgo; i += 4) {
        int s0 = __shfl(sid, i, 64);
        int s1 = __shfl(sid, i + 1, 64);
        int s2 = __shfl(sid, i + 2, 64);
        int s3 = __shfl(sid, i + 3, 64);
        float4 v0 = *(const float4*)(x_var + (long)s0 * HD + lane * 4);
        float4 v1 = *(const float4*)(x_var + (long)s1 * HD + lane * 4);
        float4 v2 = *(const float4*)(x_var + (long)s2 * HD + lane * 4);
        float4 v3 = *(const float4*)(x_var + (long)s3 * HD + lane * 4);
        float w1 = (i + 1 < cgo) ? 1.f : 0.f;
        float w2 = (i + 2 < cgo) ? 1.f : 0.f;
        float w3 = (i + 3 < cgo) ? 1.f : 0.f;
        a0 += v0.x + v1.x * w1 + v2.x * w2 + v3.x * w3;
        a1 += v0.y + v1.y * w1 + v2.y * w2 + v3.y * w3;
        a2 += v0.z + v1.z * w1 + v2.z * w2 + v3.z * w3;
        a3 += v0.w + v1.w * w1 + v2.w * w2 + v3.w * w3;
    }
    float sc = 1.0f / ((float)cnt + DEG_EPS);
    s16x4 o;
    o[0] = (short)f2bf(a0 * sc); o[1] = (short)f2bf(a1 * sc);
    o[2] = (short)f2bf(a2 * sc); o[3] = (short)f2bf(a3 * sc);
    *(s16x4*)(agg + (long)row * HD + lane * 4) = o;
}

// GEMM1, weight-stationary: wave w holds W1 rows [w*64,w*64+64) as B-frags
// in 128 VGPRs (loaded once). Grid-stride over 16-row tiles; per tile
// 8 A-loads + 32 MFMAs (4 indep chains). Epilogue transposes D-layout to
// row-major bf16 via LDS and overwrites agg in place (M).
#define C1 264
__global__ __launch_bounds__(256) void g1_kernel(
    unsigned short* __restrict__ agg,      // in: agg, out: M (in-place)
    const int* __restrict__ counts, const unsigned short* __restrict__ w1b,
    const float* __restrict__ msg_b, int num_con, int ntiles) {

    __shared__ unsigned short sT[2][16 * C1];
    const int tid = threadIdx.x, w = tid >> 6, lane = tid & 63;
    const int lr = lane & 15, lg = lane >> 4;

    short8 bfr[4][8];
#pragma unroll
    for (int jt = 0; jt < 4; ++jt)
#pragma unroll
        for (int ks = 0; ks < 8; ++ks)
            bfr[jt][ks] = *(const short8*)(w1b + (w * 64 + jt * 16 + lr) * HD + lg * 8 + ks * 32);
    float bj[4];
#pragma unroll
    for (int jt = 0; jt < 4; ++jt) bj[jt] = msg_b[w * 64 + jt * 16 + lr];

    int buf = 0;
#pragma unroll 1
    for (int rt = blockIdx.x; rt < ntiles; rt += gridDim.x) {
        int r0 = rt * 16;
        int arc = min(r0 + lr, num_con - 1);
        const unsigned short* ap = agg + (long)arc * HD + lg * 8;
        short8 af[8];
#pragma unroll
        for (int ks = 0; ks < 8; ++ks) af[ks] = *(const short8*)(ap + ks * 32);

        f32x4 acc[4] = {{0.f,0.f,0.f,0.f},{0.f,0.f,0.f,0.f},{0.f,0.f,0.f,0.f},{0.f,0.f,0.f,0.f}};
#pragma unroll
        for (int ks = 0; ks < 8; ++ks)
#pragma unroll
            for (int jt = 0; jt < 4; ++jt)
                acc[jt] = __builtin_amdgcn_mfma_f32_16x16x32_bf16(af[ks], bfr[jt][ks], acc[jt], 0, 0, 0);

        float trow[4];
#pragma unroll
        for (int q = 0; q < 4; ++q) {
            int rr = r0 + lg * 4 + q;
            float dvq = (rr < num_con) ? (float)counts[rr] : 0.f;
            trow[q] = dvq / (dvq + DEG_EPS);
        }
#pragma unroll
        for (int jt = 0; jt < 4; ++jt)
#pragma unroll
            for (int q = 0; q < 4; ++q) {
                float m = acc[jt][q] + trow[q] * bj[jt];
                sT[buf][(lg * 4 + q) * C1 + w * 64 + jt * 16 + lr] = f2bf(m);
            }
        __syncthreads();
        {
            int row = tid >> 4, seg = tid & 15;
            int grow = r0 + row;
            if (grow < num_con) {
                const unsigned short* sp = &sT[buf][row * C1 + seg * 16];
                short8 v0 = *(const short8*)(sp);
                short8 v1 = *(const short8*)(sp + 8);
                unsigned short* gp = agg + (long)grow * HD + seg * 16;
                *(short8*)gp = v0;
                *(short8*)(gp + 8) = v1;
            }
        }
        buf ^= 1;
    }
}

// GEMM2, weight-stationary: same structure; epilogue adds clue column +
// bias, ReLU, parks z fp32 in LDS, then per-row LN (16 thr/row, shfl_xor)
// and fully coalesced float4 stores.
#define C2 260
__global__ __launch_bounds__(256) void g2_kernel(
    const unsigned short* __restrict__ M, const float* __restrict__ clue,
    const unsigned short* __restrict__ w2b, const float* __restrict__ ucol,
    const float* __restrict__ upd_b,
    const float* __restrict__ ln_w, const float* __restrict__ ln_b,
    float* __restrict__ out, int num_con, int ntiles) {

    __shared__ float sZ[2][16 * C2];
    const int tid = threadIdx.x, w = tid >> 6, lane = tid & 63;
    const int lr = lane & 15, lg = lane >> 4;

    short8 bfr[4][8];
#pragma unroll
    for (int jt = 0; jt < 4; ++jt)
#pragma unroll
        for (int ks = 0; ks < 8; ++ks)
            bfr[jt][ks] = *(const short8*)(w2b + (w * 64 + jt * 16 + lr) * HD + lg * 8 + ks * 32);
    float uc[4], b2[4];
#pragma unroll
    for (int jt = 0; jt < 4; ++jt) {
        uc[jt] = ucol[w * 64 + jt * 16 + lr];
        b2[jt] = upd_b[w * 64 + jt * 16 + lr];
    }
    // per-thread LN params for cols seg*16..seg*16+15 (store phase)
    const int seg = tid & 15;
    f32x4 lw[4], lb[4];
#pragma unroll
    for (int k = 0; k < 4; ++k) {
        lw[k] = *(const f32x4*)(ln_w + seg * 16 + k * 4);
        lb[k] = *(const f32x4*)(ln_b + seg * 16 + k * 4);
    }

    int buf = 0;
#pragma unroll 1
    for (int rt = blockIdx.x; rt < ntiles; rt += gridDim.x) {
        int r0 = rt * 16;
        int arc = min(r0 + lr, num_con - 1);
        const unsigned short* ap = M + (long)arc * HD + lg * 8;
        short8 af[8];
#pragma unroll
        for (int ks = 0; ks < 8; ++ks) af[ks] = *(const short8*)(ap + ks * 32);

        f32x4 acc[4] = {{0.f,0.f,0.f,0.f},{0.f,0.f,0.f,0.f},{0.f,0.f,0.f,0.f},{0.f,0.f,0.f,0.f}};
#pragma unroll
        for (int ks = 0; ks < 8; ++ks)
#pragma unroll
            for (int jt = 0; jt < 4; ++jt)
                acc[jt] = __builtin_amdgcn_mfma_f32_16x16x32_bf16(af[ks], bfr[jt][ks], acc[jt], 0, 0, 0);

        float cl[4];
#pragma unroll
        for (int q = 0; q < 4; ++q)
            cl[q] = clue[min(r0 + lg * 4 + q, num_con - 1)];
#pragma unroll
        for (int jt = 0; jt < 4; ++jt)
#pragma unroll
            for (int q = 0; q < 4; ++q) {
                float z = fmaxf(acc[jt][q] + uc[jt] * cl[q] + b2[jt], 0.0f);
                sZ[buf][(lg * 4 + q) * C2 + w * 64 + jt * 16 + lr] = z;
            }
        __syncthreads();
        {
            int row = tid >> 4;
            const float* zp = &sZ[buf][row * C2 + seg * 16];
            f32x4 z4[4];
            float s = 0.f, s2 = 0.f;
#pragma unroll
            for (int k = 0; k < 4; ++k) {
                z4[k] = *(const f32x4*)(zp + k * 4);
#pragma unroll
                for (int e = 0; e < 4; ++e) { s += z4[k][e]; s2 += z4[k][e] * z4[k][e]; }
            }
#pragma unroll
            for (int m = 1; m < 16; m <<= 1) {
                s  += __shfl_xor(s,  m, 64);
                s2 += __shfl_xor(s2, m, 64);
            }
            float mu = s * (1.0f / HD);
            float var = s2 * (1.0f / HD) - mu * mu;
            float rs = rsqrtf(var + LN_EPS);
            int grow = r0 + row;
            if (grow < num_con) {
                float* gp = out + (long)grow * HD + seg * 16;
#pragma unroll
                for (int k = 0; k < 4; ++k) {
                    f32x4 o;
#pragma unroll
                    for (int e = 0; e < 4; ++e)
                        o[e] = (z4[k][e] - mu) * rs * lw[k][e] + lb[k][e];
                    *(f32x4*)(gp + k * 4) = o;
                }
            }
        }
        buf ^= 1;
    }
}

extern "C" void kernel_launch(void* const* d_in, const int* in_sizes, int n_in,
                              void* d_out, int out_size, void* d_ws, size_t ws_size,
                              hipStream_t stream) {
    const float* x_var = (const float*)d_in[0];
    const int*   src   = (const int*)d_in[1];
    const int*   dst   = (const int*)d_in[2];
    const float* clue  = (const float*)d_in[3];
    // d_in[4] = num_con scalar (derived from out_size instead)
    const float* msg_W = (const float*)d_in[5];
    const float* msg_b = (const float*)d_in[6];
    const float* upd_W = (const float*)d_in[7];
    const float* upd_b = (const float*)d_in[8];
    const float* ln_w  = (const float*)d_in[9];
    const float* ln_b  = (const float*)d_in[10];

    int E = in_sizes[1];
    int num_con = out_size / HD;
    int ntiles = (num_con + 15) / 16;

    char* ws = (char*)d_ws;
    int* counts = (int*)ws;                               // num_con ints
    int* eidx   = (int*)(ws + (((size_t)num_con * 4 + 255) & ~(size_t)255));
    char* after = (char*)(eidx + (size_t)num_con * CAP);  // num_con*CAP ints
    size_t aoff = ((size_t)(after - ws) + 255) & ~(size_t)255;
    unsigned short* agg = (unsigned short*)(ws + aoff);   // num_con*256 bf16 (also M)
    size_t woff = (aoff + (size_t)num_con * HD * 2 + 255) & ~(size_t)255;
    unsigned short* w1b = (unsigned short*)(ws + woff);
    unsigned short* w2b = w1b + 256 * 256;
    float* ucol = (float*)(w2b + 256 * 256);

    (void)hipMemsetAsync(counts, 0, (size_t)num_con * 4, stream);

    prep_kernel<<<256, 256, 0, stream>>>(msg_W, upd_W, w1b, w2b, ucol);

    fill_kernel<<<(E + 255) / 256, 256, 0, stream>>>(src, dst, counts, eidx, E);

    gather_kernel<<<(num_con + 3) / 4, 256, 0, stream>>>(
        x_var, counts, eidx, agg, num_con);

    g1_kernel<<<512, 256, 0, stream>>>(agg, counts, w1b, msg_b, num_con, ntiles);

    g2_kernel<<<512, 256, 0, stream>>>(agg, clue, w2b, ucol, upd_b, ln_w, ln_b,
                                       (float*)d_out, num_con, ntiles);
}